// Round 4
// baseline (117.164 us; speedup 1.0000x reference)
//
#include <hip/hip_runtime.h>
#include <math.h>

// Problem constants
constexpr int KDIM  = 784;   // feature dim
constexpr int NA    = 30;    // number of angles
constexpr int KC    = 64;    // k-chunk columns
constexpr int ROWS  = 64;    // rows per block
constexpr int NW    = 8;     // waves per block
constexpr int NT    = NW * 64;   // 512 threads
constexpr int APT   = 4;     // angles per thread (wave-uniform)
constexpr int NCH   = 12;    // full chunks: 12*64 = 768
constexpr int KTAIL = 16;    // 784 - 768

__global__ __launch_bounds__(NT, 4)   // 4 blocks/CU * 8 waves = 32 waves/CU -> 64-VGPR cap
void fused_rnn_circuit(const float* __restrict__ X,
                       const float* __restrict__ W,
                       const float* __restrict__ Bv,
                       float* __restrict__ out)
{
    const int t    = threadIdx.x;
    const int lane = t & 63;
    const int w    = t >> 6;                 // wave id 0..7
    const long long row0 = (long long)blockIdx.x * ROWS;

    // chunk tile: 64 rows x 64 floats (16 KB) x 2 buffers = 32 KB total LDS.
    // slot s (16B): row = s>>4, pos p = s&15 holds global colblock
    // g = (p&8) | ((p&7) ^ (row&7))   [XOR source swizzle, involution]
    __shared__ float xs[2][ROWS * KC];

    // ---- staging: 1024 slots/chunk, 512 threads -> 2 global_load_lds each ----
    // call A: slot t (rows 0..31), call B: slot 512+t (rows 32..63); same g for both.
    const int srow = t >> 4;                 // 0..31
    const int p    = t & 15;
    const int g    = (p & 8) | ((p & 7) ^ (srow & 7));
    const float* gsrc0 = X + (row0 + srow)      * (long long)KDIM + g * 4;
    const float* gsrc1 = gsrc0 + 32 * (long long)KDIM;

    auto stage = [&](int c, int buf) {
        const float* g0 = gsrc0 + c * KC;
        const float* g1 = gsrc1 + c * KC;
        __builtin_amdgcn_global_load_lds(
            (const __attribute__((address_space(1))) void*)g0,
            (__attribute__((address_space(3))) void*)&xs[buf][w * 256], 16, 0, 0);
        __builtin_amdgcn_global_load_lds(
            (const __attribute__((address_space(1))) void*)g1,
            (__attribute__((address_space(3))) void*)&xs[buf][2048 + w * 256], 16, 0, 0);
    };

    // ---- compute roles: row r = lane; angles w*4 .. w*4+3 (clamped, wave-uniform) ----
    const int r  = lane;
    const int rx = r & 7;
    int arj[APT];
#pragma unroll
    for (int j = 0; j < APT; ++j) {
        int a = w * APT + j;
        arj[j] = __builtin_amdgcn_readfirstlane(a < NA ? a : NA - 1);
    }

    float acc[APT];
#pragma unroll
    for (int j = 0; j < APT; ++j) acc[j] = 0.f;

    // prologue
    stage(0, 0);
    __syncthreads();

    for (int c = 0; c < NCH; ++c) {
        const int buf = c & 1;
        if (c + 1 < NCH) stage(c + 1, buf ^ 1);

        // two half-chunks of 32 columns each: keeps xv at 32 VGPRs
#pragma unroll
        for (int h = 0; h < 2; ++h) {
            float xv[32];
#pragma unroll
            for (int q = 0; q < 8; ++q) {
                const int pp = h * 8 + (q ^ rx);          // stored position of colblock h*8+q
                float4 v = *reinterpret_cast<const float4*>(&xs[buf][r * KC + pp * 4]);
                xv[4 * q + 0] = v.x; xv[4 * q + 1] = v.y;
                xv[4 * q + 2] = v.z; xv[4 * q + 3] = v.w;
            }
#pragma unroll
            for (int j = 0; j < APT; ++j) {
                const float* wr = W + (long long)arj[j] * KDIM + c * KC + h * 32;  // SGPR base
                float s = acc[j];
#pragma unroll
                for (int k = 0; k < 32; ++k) s = fmaf(xv[k], wr[k], s);
                acc[j] = s;
            }
        }
        __syncthreads();   // drains chunk c+1 loads; protects double-buffer reuse
    }

    // ---- tail: columns 768..783, direct global (one cacheline per row) ----
    {
        const float* xt = X + (row0 + r) * (long long)KDIM + NCH * KC;
        float xv[KTAIL];
#pragma unroll
        for (int q = 0; q < 4; ++q) {
            float4 v = *reinterpret_cast<const float4*>(xt + 4 * q);
            xv[4 * q + 0] = v.x; xv[4 * q + 1] = v.y;
            xv[4 * q + 2] = v.z; xv[4 * q + 3] = v.w;
        }
#pragma unroll
        for (int j = 0; j < APT; ++j) {
            const float* wr = W + (long long)arj[j] * KDIM + NCH * KC;
            float s = acc[j];
#pragma unroll
            for (int k = 0; k < KTAIL; ++k) s = fmaf(xv[k], wr[k], s);
            acc[j] = s;
        }
    }

    // ---- gather angles (+bias) into LDS, aliased into xs[0] (free after last barrier) ----
    float (*ang)[33] = reinterpret_cast<float (*)[33]>(&xs[0][0]);   // 64*33*4 = 8.4 KB < 16 KB
#pragma unroll
    for (int j = 0; j < APT; ++j) {
        int a = w * APT + j;
        if (a < NA) ang[r][a] = acc[j] + Bv[a];
    }
    __syncthreads();

    // ---- circuit: wave 0 only, one thread per row ----
    if (t < 64) {
        const float* ap = ang[t];

        float sr[16], si[16];
#pragma unroll
        for (int q = 0; q < 16; ++q) { sr[q] = 0.f; si[q] = 0.f; }
        sr[0] = 1.f;

        auto u3 = [&](int wq, float th, float ph, float la) {
            float ch, sh;  __sincosf(0.5f * th, &sh, &ch);
            float elr, eli; __sincosf(la, &eli, &elr);
            float epr, epi; __sincosf(ph, &epi, &epr);
            float eer = epr * elr - epi * eli;   // ep*el
            float eei = epr * eli + epi * elr;
            const int m = 1 << (3 - wq);
#pragma unroll
            for (int idx = 0; idx < 16; ++idx) {
                if (idx & m) continue;
                int i1 = idx + m;
                float o0r = sr[idx], o0i = si[idx], o1r = sr[i1], o1i = si[i1];
                float e1r = elr * o1r - eli * o1i;
                float e1i = elr * o1i + eli * o1r;
                sr[idx] = ch * o0r - sh * e1r;
                si[idx] = ch * o0i - sh * e1i;
                float p0r = epr * o0r - epi * o0i;
                float p0i = epr * o0i + epi * o0r;
                float q1r = eer * o1r - eei * o1i;
                float q1i = eer * o1i + eei * o1r;
                sr[i1] = sh * p0r + ch * q1r;
                si[i1] = sh * p0i + ch * q1i;
            }
        };

#pragma unroll
        for (int lay = 0; lay < 2; ++lay) {
            const int base = lay * 15;
#pragma unroll
            for (int i = 0; i < 3; ++i) {
                {
                    float th = ap[base + i * 4];
                    float ch, sh; __sincosf(0.5f * th, &sh, &ch);
                    const int m1 = 1 << (3 - i);
                    const int m2 = 1 << (2 - i);
#pragma unroll
                    for (int b0 = 0; b0 < 16; ++b0) {
                        if (b0 & (m1 | m2)) continue;
                        int i00 = b0, i01 = b0 + m2, i10 = b0 + m1, i11 = b0 + m1 + m2;
                        float o00r = sr[i00], o00i = si[i00], o11r = sr[i11], o11i = si[i11];
                        sr[i00] = ch * o00r + sh * o11i;
                        si[i00] = ch * o00i - sh * o11r;
                        sr[i11] = ch * o11r + sh * o00i;
                        si[i11] = ch * o11i - sh * o00r;
                        float o01r = sr[i01], o01i = si[i01], o10r = sr[i10], o10i = si[i10];
                        sr[i01] = ch * o01r + sh * o10i;
                        si[i01] = ch * o01i - sh * o10r;
                        sr[i10] = ch * o10r + sh * o01i;
                        si[i10] = ch * o10i - sh * o01r;
                    }
                }
                u3(i, ap[base + i * 4 + 1], ap[base + i * 4 + 2], ap[base + i * 4 + 3]);
            }
            u3(3, ap[base + 12], ap[base + 13], ap[base + 14]);
        }

        float* orow = out + (row0 + t) * 32;
#pragma unroll
        for (int q = 0; q < 8; ++q) {
            float4 v = make_float4(sr[2 * q], si[2 * q], sr[2 * q + 1], si[2 * q + 1]);
            *reinterpret_cast<float4*>(orow + q * 4) = v;
        }
    }
}

extern "C" void kernel_launch(void* const* d_in, const int* in_sizes, int n_in,
                              void* d_out, int out_size, void* d_ws, size_t ws_size,
                              hipStream_t stream) {
    const float* X  = (const float*)d_in[0];
    const float* W  = (const float*)d_in[1];
    const float* Bv = (const float*)d_in[2];
    float* out = (float*)d_out;

    const int Bn = in_sizes[0] / KDIM;   // 65536
    dim3 grid(Bn / ROWS);                // 1024 blocks x 512 threads, 4 blocks/CU
    fused_rnn_circuit<<<grid, NT, 0, stream>>>(X, W, Bv, out);
}